// Round 17
// baseline (8487.857 us; speedup 1.0000x reference)
//
#include <hip/hip_runtime.h>
#include <cstddef>
#include <cstdint>

// Problem constants: M,B,L,S,Q = 2,64,512,26,512
#define M_ 2
#define B_ 64
#define L_ 512
#define S_ 26
#define Q_ 512
#define NT 1024                 // 16 waves = 2 independent 8-wave units
#define LB 16
#define TSCALE 256.0f           // trans fp8 scale
#define ETS (1.0f / 256.0f)     // folded into packed emit: cancels TSCALE each step
#define LN2F 0.6931471805599453f

typedef float f32x4 __attribute__((ext_vector_type(4)));
typedef short bfrag8 __attribute__((ext_vector_type(8)));               // 8 bf16
typedef int   i32x8  __attribute__((ext_vector_type(8)));               // 32B MFMA operand
typedef unsigned long long u64x2 __attribute__((ext_vector_type(2)));   // 16B LDS read

// workgroup barrier WITHOUT the vmcnt(0) drain __syncthreads carries.
#define BARRIER() asm volatile("s_waitcnt lgkmcnt(0)\n\ts_barrier" ::: "memory")

// ---- DPP helpers ----
template <int CTRL>
__device__ __forceinline__ float dpp_add(float v) {
    int x = __builtin_amdgcn_update_dpp(0, __builtin_bit_cast(int, v), CTRL, 0xF, 0xF, true);
    return v + __builtin_bit_cast(float, x);
}
__device__ __forceinline__ float red16(float v) {
    v = dpp_add<0xB1>(v);   // lane^1
    v = dpp_add<0x4E>(v);   // lane^2
    v = dpp_add<0x141>(v);  // row_half_mirror (quad^1)
    v = dpp_add<0x140>(v);  // row_mirror      (quad^3)
    return v;
}

// ---- encoders ----
__device__ __forceinline__ uint32_t enc_e4m3(float f) {
    if (!(f > 0.f)) return 0u;
    float v = fminf(f, 448.f);
    if (v < 0.015625f) return (uint32_t)rintf(v * 512.f);
    uint32_t u = __float_as_uint(v);
    u += 0x7FFFFu + ((u >> 20) & 1u);
    uint32_t e2  = ((u >> 23) & 0xffu) - 120u;
    uint32_t man = (u >> 20) & 7u;
    if (e2 > 15u || (e2 == 15u && man > 6u)) return 0x7Eu;
    return (e2 << 3) | man;
}
__device__ __forceinline__ uint32_t enc_bf16(float f) {
    uint32_t u = __float_as_uint(f);
    u += 0x7fffu + ((u >> 16) & 1u);      // RNE
    return u >> 16;
}

// ---- prep 1: trans*256 -> fp8 B-fragments for 16x16x128 MX MFMA ----
// PERMUTED k-axis: ps = wp*64 + cq*4 + ntq <-> s = wp*64 + ntq*16 + cq.
__global__ void pack_trans_frag(const float* __restrict__ trans,
                                uint32_t* __restrict__ Bf) {
    int idx  = blockIdx.x * blockDim.x + threadIdx.x;  // M*8*4*4*64 = 16384
    int lane = idx & 63;
    int kt   = (idx >> 6) & 3;
    int nt   = (idx >> 8) & 3;
    int wave = (idx >> 10) & 7;
    int m    = idx >> 13;
    int col  = wave * 64 + nt * 16 + (lane & 15);
    const float* tm = trans + (size_t)m * Q_ * Q_;
    uint32_t w[8];
#pragma unroll
    for (int d = 0; d < 8; ++d) {
        uint32_t v = 0;
#pragma unroll
        for (int b = 0; b < 4; ++b) {
            int j  = d * 4 + b;
            int ps = kt * 128 + (lane >> 4) * 32 + j;
            int s  = (ps & ~63) + (ps & 3) * 16 + ((ps >> 2) & 15);  // un-permute
            v |= enc_e4m3(tm[(size_t)s * Q_ + col] * TSCALE) << (8 * b);
        }
        w[d] = v;
    }
    uint32_t* dst = Bf + (size_t)idx * 8;
    *(uint4*)dst       = make_uint4(w[0], w[1], w[2], w[3]);
    *(uint4*)(dst + 4) = make_uint4(w[4], w[5], w[6], w[7]);
}

// ---- prep 2: emit*ETS -> bf16 B-fragments (K=32, s>=26 zero) ----
__global__ void pack_emit_frag(const float* __restrict__ emit, uint4* __restrict__ Ef) {
    int idx  = blockIdx.x * blockDim.x + threadIdx.x;  // M*8*4*64 = 4096
    int lane = idx & 63;
    int nt   = (idx >> 6) & 3;
    int wave = (idx >> 8) & 7;
    int m    = idx >> 11;
    int col  = wave * 64 + nt * 16 + (lane & 15);
    int s0   = (lane >> 4) * 8;
    uint32_t h[8];
#pragma unroll
    for (int i = 0; i < 8; ++i) {
        int s = s0 + i;
        h[i] = (s < S_) ? enc_bf16(emit[((size_t)m * S_ + s) * Q_ + col] * ETS) : 0u;
    }
    Ef[idx] = make_uint4(h[0] | (h[1] << 16), h[2] | (h[3] << 16),
                         h[4] | (h[5] << 16), h[6] | (h[7] << 16));
}

// ---- prep 3: inputs -> bf16 A-fragments per (group,t) ----
__global__ void pack_inputs_frag(const float* __restrict__ inputs, uint4* __restrict__ Af) {
    int idx  = blockIdx.x * blockDim.x + threadIdx.x;  // M*4*512*64 = 262144
    int lane = idx & 63;
    int t    = (idx >> 6) & 511;
    int bg   = (idx >> 15) & 3;
    int m    = idx >> 17;
    int colq = lane & 15, krow = lane >> 4;
    int b    = bg * 16 + colq;
    int k0   = krow * 8;
    const float* ip = inputs + ((size_t)(m * B_ + b) * L_ + t) * S_ + k0;
    uint32_t h[8];
#pragma unroll
    for (int i = 0; i < 8; ++i)
        h[i] = (k0 + i < S_) ? enc_bf16(ip[i]) : 0u;
    Af[((size_t)(m * 4 + bg) * L_ + t) * 64 + lane] =
        make_uint4(h[0] | (h[1] << 16), h[2] | (h[3] << 16),
                   h[4] | (h[5] << 16), h[6] | (h[7] << 16));
}

// ---- main: MX-scaled fp8 K=128 recursion, TWO independent 16-row units/block ----
// unit u = wave>>3 (waves 0-7 = unit 0, 8-15 = unit 1); private alpha/wsB per unit.
// alpha LDS (16 rows x 512B): byte(row,ps) = row*512 + ((ps>>4)^(row&7))*16 + (ps&15).
__global__ __launch_bounds__(NT, 1) void hmm_fwd_mfma(
    const float* __restrict__ init_dist,
    const uint32_t* __restrict__ Bf,
    const uint4* __restrict__ Ef,
    const uint4* __restrict__ Af,
    float* __restrict__ out)
{
    __shared__ char alpha8[2][2][16 * Q_];   // [unit][buf]
    __shared__ char wsB[2][2][8 * 4 * 16];   // [unit][buf][wave][krow] : f32x4

    const int tid  = threadIdx.x;
    const int wave = tid >> 6;             // 0..15
    const int u    = wave >> 3;            // unit 0/1
    const int wv   = wave & 7;             // wave-in-unit
    const int lane = tid & 63;
    const int colq = lane & 15;
    const int krow = lane >> 4;
    const int bid  = blockIdx.x;           // 0..3
    const int g16  = bid * 2 + u;          // 16-row group 0..7
    const int m    = g16 >> 2;
    const int bg   = g16 & 3;
    const int b0   = bg * 16;

    char* aun[2] = { alpha8[u][0], alpha8[u][1] };
    char* wun[2] = { wsB[u][0], wsB[u][1] };

    // B fragments (trans, fp8): 4nt x 4kt x 8 VGPR = 128 regs
    union Bfrag { unsigned long long q[4]; i32x8 v; };
    Bfrag bf[4][4];
    {
        const unsigned long long* bp =
            (const unsigned long long*)Bf + ((size_t)(m * 8 + wv) * 16) * 256 + lane * 4;
#pragma unroll
        for (int nt = 0; nt < 4; ++nt)
#pragma unroll
            for (int kt = 0; kt < 4; ++kt) {
                const unsigned long long* f = bp + (size_t)(nt * 4 + kt) * 256;
#pragma unroll
                for (int h = 0; h < 4; ++h) bf[nt][kt].q[h] = f[h];
            }
#pragma unroll
        for (int nt = 0; nt < 4; ++nt)
#pragma unroll
            for (int kt = 0; kt < 4; ++kt)
#pragma unroll
                for (int h = 0; h < 4; ++h)
                    asm volatile("" : "+v"(bf[nt][kt].q[h]));
    }
    // emit B fragments (bf16)
    bfrag8 ef[4];
#pragma unroll
    for (int nt = 0; nt < 4; ++nt)
        ef[nt] = __builtin_bit_cast(bfrag8,
            Ef[(((size_t)m * 8 + wv) * 4 + nt) * 64 + lane]);

    const uint4* ab = Af + ((size_t)(m * 4 + bg) * L_) * 64 + lane;   // +64 per t

    float* ebase  = out + (size_t)(m * B_ + b0) * L_ * Q_;   // [row][t][col]
    float* ll_out = out + (size_t)M_ * B_ * L_ * Q_;

    float* rp[4];
#pragma unroll
    for (int r = 0; r < 4; ++r)
        rp[r] = ebase + (size_t)(krow * 4 + r) * (L_ * Q_) + wv * 64 + colq;

    // alpha write offsets: one u32 per row at psbase = wv*64 + colq*4
    int woff[4];
    {
        const int slot = wv * 4 + (colq >> 2);
        const int bis  = (colq & 3) << 2;
#pragma unroll
        for (int r = 0; r < 4; ++r) {
            int row = krow * 4 + r;
            woff[r] = row * 512 + ((slot ^ (row & 7)) << 4) + bis;
        }
    }
    // A-frag read offsets: 2 per kt
    int roff[4][2];
#pragma unroll
    for (int kt = 0; kt < 4; ++kt) {
        int s0 = kt * 8 + krow * 2;
        roff[kt][0] = colq * 512 + ((s0 ^ (colq & 7)) << 4);
        roff[kt][1] = colq * 512 + (((s0 + 1) ^ (colq & 7)) << 4);
    }

    const int wroff = ((colq & 7) * 4 + krow) * 16;
    const int wwoff = (wv * 4 + krow) * 16;

    float a[4][4];
    int   llE[4];
    int   Eprev[4];

    // ================= t = 0 =================
    uint4 ain = ab[0];
    {
        bfrag8 av = __builtin_bit_cast(bfrag8, ain);
        f32x4 ce[4];
#pragma unroll
        for (int nt = 0; nt < 4; ++nt) {
            ce[nt] = f32x4{0, 0, 0, 0};
            ce[nt] = __builtin_amdgcn_mfma_f32_16x16x32_bf16(av, ef[nt], ce[nt], 0, 0, 0);
        }
#pragma unroll
        for (int nt = 0; nt < 4; ++nt) {
            float iv = init_dist[m * Q_ + wv * 64 + nt * 16 + colq];
#pragma unroll
            for (int r = 0; r < 4; ++r)
                a[nt][r] = iv * ce[nt][r];
        }
        float p[4];
#pragma unroll
        for (int r = 0; r < 4; ++r)
            p[r] = red16(a[0][r] + a[1][r] + a[2][r] + a[3][r]);
        if (colq == 0) *(f32x4*)(wun[0] + wwoff) = f32x4{p[0], p[1], p[2], p[3]};
        __syncthreads();
        f32x4 sv = *(const f32x4*)(wun[0] + wroff);
#pragma unroll
        for (int r = 0; r < 4; ++r) {
            float shat = red16(sv[r]) * 0.5f;
            int D = (int)((__float_as_uint(shat) >> 23) & 0xffu) - 127;
            int E = D - 11;
            llE[r] = E; Eprev[r] = E;
            float kf = __uint_as_float((uint32_t)(127 - E) << 23);
            uint32_t pk = __builtin_amdgcn_cvt_pk_fp8_f32(
                fminf(a[0][r] * kf, 448.f), fminf(a[1][r] * kf, 448.f), 0, false);
            pk = __builtin_amdgcn_cvt_pk_fp8_f32(
                fminf(a[2][r] * kf, 448.f), fminf(a[3][r] * kf, 448.f), pk, true);
            *(uint32_t*)(&aun[0][woff[r]]) = pk;
        }
        __syncthreads();
    }
    uint4 ain_next = ab[64];   // t = 1

    // ================= t = 1 .. L-1 : ONE lgkm-only barrier per step ============
    for (int t = 1; t < L_; ++t) {
        const int pb = (t - 1) & 1, qb = t & 1;

        ain = ain_next;
        int tn = (t + 1 < L_) ? (t + 1) : t;
        ain_next = ab[(size_t)tn * 64];            // stays in flight across barrier

        // shadow: previous step's true row-sum -> inv, E, kf
        f32x4 sv = *(const f32x4*)(wun[pb] + wroff);
        float inv[4], kf[4];
        int Ecur[4];
#pragma unroll
        for (int r = 0; r < 4; ++r) {
            float shat = red16(sv[r]) * 0.5f;
            inv[r] = __builtin_amdgcn_rcpf(shat);
            int D = (int)((__float_as_uint(shat) >> 23) & 0xffu) - 127;
            Ecur[r] = D - Eprev[r] - 12;
            kf[r] = __uint_as_float((uint32_t)(127 - Ecur[r]) << 23);
        }

        // deferred normalized store of forward_{t-1}
#pragma unroll
        for (int r = 0; r < 4; ++r) rp[r] += Q_;
#pragma unroll
        for (int nt = 0; nt < 4; ++nt)
#pragma unroll
            for (int r = 0; r < 4; ++r)
                rp[r][nt * 16 - Q_] = a[nt][r] * inv[r];

        // MFMA block: 4 kt x (2 b128 A-reads + 4 MX MFMAs) + interleaved e-MFMA
        bfrag8 av = __builtin_bit_cast(bfrag8, ain);
        f32x4 c[4], ce[4];
#pragma unroll
        for (int nt = 0; nt < 4; ++nt) { c[nt] = f32x4{0,0,0,0}; ce[nt] = f32x4{0,0,0,0}; }
        __builtin_amdgcn_s_setprio(1);
#pragma unroll
        for (int kt = 0; kt < 4; ++kt) {
            union Afrag { u64x2 h[2]; i32x8 v; } afr;
            afr.h[0] = *(const u64x2*)(&aun[pb][roff[kt][0]]);
            afr.h[1] = *(const u64x2*)(&aun[pb][roff[kt][1]]);
            ce[kt] = __builtin_amdgcn_mfma_f32_16x16x32_bf16(av, ef[kt], ce[kt], 0, 0, 0);
#pragma unroll
            for (int nt = 0; nt < 4; ++nt)
                c[nt] = __builtin_amdgcn_mfma_scale_f32_16x16x128_f8f6f4(
                            afr.v, bf[nt][kt].v, c[nt],
                            0, 0,                    // cbsz=fp8, blgp=fp8
                            0, 0x7F7F7F7F,           // scale A = 1.0
                            0, 0x7F7F7F7F);          // scale B = 1.0
        }
        __builtin_amdgcn_s_setprio(0);

        // â_t = ĉ · ê_t ; quantize+write alpha first, then row sums
#pragma unroll
        for (int nt = 0; nt < 4; ++nt)
#pragma unroll
            for (int r = 0; r < 4; ++r)
                a[nt][r] = c[nt][r] * ce[nt][r];

        if (t < L_ - 1) {
#pragma unroll
            for (int r = 0; r < 4; ++r) {
                llE[r] += Ecur[r]; Eprev[r] = Ecur[r];
                float k = kf[r];
                uint32_t pk = __builtin_amdgcn_cvt_pk_fp8_f32(
                    fminf(a[0][r] * k, 448.f), fminf(a[1][r] * k, 448.f), 0, false);
                pk = __builtin_amdgcn_cvt_pk_fp8_f32(
                    fminf(a[2][r] * k, 448.f), fminf(a[3][r] * k, 448.f), pk, true);
                *(uint32_t*)(&aun[qb][woff[r]]) = pk;
            }
        }

        float p[4];
#pragma unroll
        for (int r = 0; r < 4; ++r)
            p[r] = red16(a[0][r] + a[1][r] + a[2][r] + a[3][r]);
        if (colq == 0) *(f32x4*)(wun[qb] + wwoff) = f32x4{p[0], p[1], p[2], p[3]};

        BARRIER();
    }

    // ================= final: normalize t = L-1, write ll =================
    {
        f32x4 sv = *(const f32x4*)(wun[(L_ - 1) & 1] + wroff);
        float ll[4];
#pragma unroll
        for (int r = 0; r < 4; ++r) {
            float shat = red16(sv[r]) * 0.5f;
            float invr = __builtin_amdgcn_rcpf(shat);
#pragma unroll
            for (int nt = 0; nt < 4; ++nt)
                rp[r][nt * 16] = a[nt][r] * invr;
            ll[r] = LN2F * (8.0f + __log2f(shat) + (float)llE[r]);
        }
        if (wv == 0 && colq == 0) {
#pragma unroll
            for (int r = 0; r < 4; ++r)
                ll_out[m * B_ + b0 + krow * 4 + r] = ll[r];
        }
    }
}

// ---- fallback path (insufficient workspace): emission prekernel + fp32 recursion ----
__global__ __launch_bounds__(512) void emission_kernel(
    const float* __restrict__ inputs, const float* __restrict__ emit,
    float* __restrict__ out) {
    __shared__ float ein[LB * S_];
    const int tid = threadIdx.x;
    const int lt  = blockIdx.x % (L_ / LB);
    const int mb  = blockIdx.x / (L_ / LB);
    const int m   = mb / B_;
    const int b   = mb % B_;
    const int k   = tid;
    const float* inrow = inputs + ((size_t)(m * B_ + b) * L_ + (size_t)lt * LB) * S_;
    if (tid < LB * S_) ein[tid] = inrow[tid];
    float emv[S_];
    const float* em = emit + (size_t)m * S_ * Q_ + k;
#pragma unroll
    for (int s = 0; s < S_; ++s) emv[s] = em[(size_t)s * Q_];
    __syncthreads();
    float* orow = out + ((size_t)(m * B_ + b) * L_ + (size_t)lt * LB) * Q_ + k;
#pragma unroll
    for (int il = 0; il < LB; ++il) {
        float e = 0.f;
#pragma unroll
        for (int s = 0; s < S_; ++s) e = fmaf(ein[il * S_ + s], emv[s], e);
        orow[(size_t)il * Q_] = e;
    }
}

__global__ __launch_bounds__(512, 1) void hmm_fwd_f32(
    const float* __restrict__ init_dist,
    const float* __restrict__ trans,
    float* __restrict__ out)
{
    __shared__ float alphaF[Q_];
    __shared__ alignas(16) float apart[4][Q_];
    __shared__ float wred[8];
    const int tid  = threadIdx.x;
    const int m    = blockIdx.x / B_;
    const int b    = blockIdx.x % B_;
    const int k    = tid;
    const int k0   = (tid & 127) * 4;
    const int qh   = tid >> 7;
    const int lane = tid & 63;
    const int wav  = tid >> 6;
    float* erow   = out + (size_t)(m * B_ + b) * L_ * Q_;
    float* ll_out = out + (size_t)M_ * B_ * L_ * Q_;
    float ll = 0.f;
    {
        float e = erow[k];
        float a = init_dist[m * Q_ + k] * e;
        float r = a;
#pragma unroll
        for (int off = 32; off; off >>= 1) r += __shfl_xor(r, off, 64);
        if (lane == 0) wred[wav] = r;
        __syncthreads();
        float s = 0.f;
#pragma unroll
        for (int w = 0; w < 8; ++w) s += wred[w];
        ll = logf(s);
        float n = a * (1.0f / s);
        alphaF[k] = n;
        erow[k] = n;
        __syncthreads();
    }
    for (int t = 1; t < L_; ++t) {
        float e = erow[(size_t)t * Q_ + k];
        float4 acc = make_float4(0.f, 0.f, 0.f, 0.f);
        const float* tg = trans + (size_t)m * Q_ * Q_ + (size_t)(qh * 128) * Q_ + k0;
#pragma unroll 4
        for (int q = 0; q < 128; ++q) {
            float4 tv = *(const float4*)(tg + (size_t)q * Q_);
            float aq = alphaF[qh * 128 + q];
            acc.x = fmaf(aq, tv.x, acc.x);
            acc.y = fmaf(aq, tv.y, acc.y);
            acc.z = fmaf(aq, tv.z, acc.z);
            acc.w = fmaf(aq, tv.w, acc.w);
        }
        *(float4*)&apart[qh][k0] = acc;
        __syncthreads();
        float avs = apart[0][k] + apart[1][k] + apart[2][k] + apart[3][k];
        float a   = avs * e;
        float r = a;
#pragma unroll
        for (int off = 32; off; off >>= 1) r += __shfl_xor(r, off, 64);
        if (lane == 0) wred[wav] = r;
        __syncthreads();
        float s = 0.f;
#pragma unroll
        for (int w = 0; w < 8; ++w) s += wred[w];
        ll += logf(s);
        float n = a * (1.0f / s);
        alphaF[k] = n;
        erow[(size_t)t * Q_ + k] = n;
        __syncthreads();
    }
    if (tid == 0) ll_out[m * B_ + b] = ll;
}

extern "C" void kernel_launch(void* const* d_in, const int* in_sizes, int n_in,
                              void* d_out, int out_size, void* d_ws, size_t ws_size,
                              hipStream_t stream) {
    const float* inputs    = (const float*)d_in[0];
    const float* init_dist = (const float*)d_in[1];
    const float* trans     = (const float*)d_in[2];
    const float* emit      = (const float*)d_in[3];
    float* out             = (float*)d_out;

    const size_t bf_bytes = (size_t)M_ * 8 * 4 * 4 * 64 * 32;      // 512 KB
    const size_t ef_bytes = (size_t)M_ * 8 * 4 * 64 * 16;          // 64 KB
    const size_t af_bytes = (size_t)M_ * 4 * L_ * 64 * 16;         // 4 MB
    const bool mfma_path = (ws_size >= bf_bytes + ef_bytes + af_bytes);

    if (mfma_path) {
        uint32_t* Bf = (uint32_t*)d_ws;
        uint4* Ef = (uint4*)((char*)d_ws + bf_bytes);
        uint4* Af = (uint4*)((char*)d_ws + bf_bytes + ef_bytes);
        hipLaunchKernelGGL(pack_trans_frag, dim3((M_ * 8 * 4 * 4 * 64) / 256), dim3(256),
                           0, stream, trans, Bf);
        hipLaunchKernelGGL(pack_emit_frag, dim3((M_ * 8 * 4 * 64) / 256), dim3(256),
                           0, stream, emit, Ef);
        hipLaunchKernelGGL(pack_inputs_frag, dim3((M_ * 4 * L_ * 64) / 256), dim3(256),
                           0, stream, inputs, Af);
        hipLaunchKernelGGL(hmm_fwd_mfma, dim3(M_ * B_ / 32), dim3(NT), 0, stream,
                           init_dist, Bf, Ef, Af, out);
    } else {
        hipLaunchKernelGGL(emission_kernel, dim3(M_ * B_ * (L_ / LB)), dim3(512), 0, stream,
                           inputs, emit, out);
        hipLaunchKernelGGL(hmm_fwd_f32, dim3(M_ * B_), dim3(512), 0, stream,
                           init_dist, trans, out);
    }
}

// Round 18
// 748.547 us; speedup vs baseline: 11.3391x; 11.3391x over previous
//
#include <hip/hip_runtime.h>
#include <cstddef>
#include <cstdint>

// Problem constants: M,B,L,S,Q = 2,64,512,26,512
#define M_ 2
#define B_ 64
#define L_ 512
#define S_ 26
#define Q_ 512
#define NT 512
#define LB 16
#define TSCALE 256.0f           // trans fp8 scale
#define ETS (1.0f / 256.0f)     // folded into packed emit: cancels TSCALE each step
#define LN2F 0.6931471805599453f

typedef float f32x4 __attribute__((ext_vector_type(4)));
typedef short bfrag8 __attribute__((ext_vector_type(8)));               // 8 bf16
typedef int   i32x8  __attribute__((ext_vector_type(8)));               // 32B MFMA operand
typedef unsigned long long u64x2 __attribute__((ext_vector_type(2)));   // 16B LDS read

// workgroup barrier WITHOUT the vmcnt(0) drain __syncthreads carries.
#define BARRIER() asm volatile("s_waitcnt lgkmcnt(0)\n\ts_barrier" ::: "memory")

// ---- DPP helpers ----
template <int CTRL>
__device__ __forceinline__ float dpp_add(float v) {
    int x = __builtin_amdgcn_update_dpp(0, __builtin_bit_cast(int, v), CTRL, 0xF, 0xF, true);
    return v + __builtin_bit_cast(float, x);
}
__device__ __forceinline__ float red16(float v) {
    v = dpp_add<0xB1>(v);   // lane^1
    v = dpp_add<0x4E>(v);   // lane^2
    v = dpp_add<0x141>(v);  // row_half_mirror (quad^1)
    v = dpp_add<0x140>(v);  // row_mirror      (quad^3)
    return v;
}

// ---- encoders ----
__device__ __forceinline__ uint32_t enc_e4m3(float f) {
    if (!(f > 0.f)) return 0u;
    float v = fminf(f, 448.f);
    if (v < 0.015625f) return (uint32_t)rintf(v * 512.f);
    uint32_t u = __float_as_uint(v);
    u += 0x7FFFFu + ((u >> 20) & 1u);
    uint32_t e2  = ((u >> 23) & 0xffu) - 120u;
    uint32_t man = (u >> 20) & 7u;
    if (e2 > 15u || (e2 == 15u && man > 6u)) return 0x7Eu;
    return (e2 << 3) | man;
}
__device__ __forceinline__ uint32_t enc_bf16(float f) {
    uint32_t u = __float_as_uint(f);
    u += 0x7fffu + ((u >> 16) & 1u);      // RNE
    return u >> 16;
}

// ---- prep 1: trans*256 -> fp8 B-fragments for 16x16x128 MX MFMA ----
// PERMUTED k-axis: ps = wp*64 + cq*4 + ntq <-> s = wp*64 + ntq*16 + cq.
__global__ void pack_trans_frag(const float* __restrict__ trans,
                                uint32_t* __restrict__ Bf) {
    int idx  = blockIdx.x * blockDim.x + threadIdx.x;  // M*8*4*4*64 = 16384
    int lane = idx & 63;
    int kt   = (idx >> 6) & 3;
    int nt   = (idx >> 8) & 3;
    int wave = (idx >> 10) & 7;
    int m    = idx >> 13;
    int col  = wave * 64 + nt * 16 + (lane & 15);
    const float* tm = trans + (size_t)m * Q_ * Q_;
    uint32_t w[8];
#pragma unroll
    for (int d = 0; d < 8; ++d) {
        uint32_t v = 0;
#pragma unroll
        for (int b = 0; b < 4; ++b) {
            int j  = d * 4 + b;
            int ps = kt * 128 + (lane >> 4) * 32 + j;
            int s  = (ps & ~63) + (ps & 3) * 16 + ((ps >> 2) & 15);  // un-permute
            v |= enc_e4m3(tm[(size_t)s * Q_ + col] * TSCALE) << (8 * b);
        }
        w[d] = v;
    }
    uint32_t* dst = Bf + (size_t)idx * 8;
    *(uint4*)dst       = make_uint4(w[0], w[1], w[2], w[3]);
    *(uint4*)(dst + 4) = make_uint4(w[4], w[5], w[6], w[7]);
}

// ---- prep 2: emit*ETS -> bf16 B-fragments (K=32, s>=26 zero) ----
__global__ void pack_emit_frag(const float* __restrict__ emit, uint4* __restrict__ Ef) {
    int idx  = blockIdx.x * blockDim.x + threadIdx.x;  // M*8*4*64 = 4096
    int lane = idx & 63;
    int nt   = (idx >> 6) & 3;
    int wave = (idx >> 8) & 7;
    int m    = idx >> 11;
    int col  = wave * 64 + nt * 16 + (lane & 15);
    int s0   = (lane >> 4) * 8;
    uint32_t h[8];
#pragma unroll
    for (int i = 0; i < 8; ++i) {
        int s = s0 + i;
        h[i] = (s < S_) ? enc_bf16(emit[((size_t)m * S_ + s) * Q_ + col] * ETS) : 0u;
    }
    Ef[idx] = make_uint4(h[0] | (h[1] << 16), h[2] | (h[3] << 16),
                         h[4] | (h[5] << 16), h[6] | (h[7] << 16));
}

// ---- prep 3: inputs -> bf16 A-fragments per (block,t) ----
__global__ void pack_inputs_frag(const float* __restrict__ inputs, uint4* __restrict__ Af) {
    int idx  = blockIdx.x * blockDim.x + threadIdx.x;  // M*4*512*64 = 262144
    int lane = idx & 63;
    int t    = (idx >> 6) & 511;
    int bg   = (idx >> 15) & 3;
    int m    = idx >> 17;
    int colq = lane & 15, krow = lane >> 4;
    int b    = bg * 16 + colq;
    int k0   = krow * 8;
    const float* ip = inputs + ((size_t)(m * B_ + b) * L_ + t) * S_ + k0;
    uint32_t h[8];
#pragma unroll
    for (int i = 0; i < 8; ++i)
        h[i] = (k0 + i < S_) ? enc_bf16(ip[i]) : 0u;
    Af[((size_t)(m * 4 + bg) * L_ + t) * 64 + lane] =
        make_uint4(h[0] | (h[1] << 16), h[2] | (h[3] << 16),
                   h[4] | (h[5] << 16), h[6] | (h[7] << 16));
}

// ---- main: MX-scaled fp8 K=128 MFMA recursion + fused bf16 emission MFMA ----
// alpha LDS (16 rows x 512B): byte(row,ps) = row*512 + ((ps>>4)^(row&7))*16 + (ps&15).
// Step schedule: [barrier] -> sv read + ALL 8 af b128 reads (LDS pipe streams
// immediately) -> shadow VALU + deferred stores under the LDS burst -> MFMA
// block consuming afq regs (compiler-counted lgkmcnt) -> tail -> [barrier].
__global__ __launch_bounds__(NT, 2) void hmm_fwd_mfma(
    const float* __restrict__ init_dist,
    const uint32_t* __restrict__ Bf,
    const uint4* __restrict__ Ef,
    const uint4* __restrict__ Af,
    float* __restrict__ out)
{
    __shared__ char alpha8[2][16 * Q_];
    __shared__ char wsB[2][8 * 4 * 16];    // [buf][wave][krow] : f32x4

    const int tid  = threadIdx.x;
    const int wave = tid >> 6;
    const int lane = tid & 63;
    const int colq = lane & 15;            // = arow for the A-read
    const int krow = lane >> 4;
    const int bid  = blockIdx.x;           // 0..7
    const int m    = bid >> 2;
    const int b0   = (bid & 3) * 16;

    // B fragments (trans, fp8): 4nt x 4kt x 8 VGPR = 128 regs
    union Bfrag { unsigned long long q[4]; i32x8 v; };
    Bfrag bf[4][4];
    {
        const unsigned long long* bp =
            (const unsigned long long*)Bf + ((size_t)(m * 8 + wave) * 16) * 256 + lane * 4;
#pragma unroll
        for (int nt = 0; nt < 4; ++nt)
#pragma unroll
            for (int kt = 0; kt < 4; ++kt) {
                const unsigned long long* f = bp + (size_t)(nt * 4 + kt) * 256;
#pragma unroll
                for (int h = 0; h < 4; ++h) bf[nt][kt].q[h] = f[h];
            }
#pragma unroll
        for (int nt = 0; nt < 4; ++nt)
#pragma unroll
            for (int kt = 0; kt < 4; ++kt)
#pragma unroll
                for (int h = 0; h < 4; ++h)
                    asm volatile("" : "+v"(bf[nt][kt].q[h]));
    }
    // emit B fragments (bf16)
    bfrag8 ef[4];
#pragma unroll
    for (int nt = 0; nt < 4; ++nt)
        ef[nt] = __builtin_bit_cast(bfrag8,
            Ef[(((size_t)m * 8 + wave) * 4 + nt) * 64 + lane]);

    const uint4* ab = Af + ((size_t)bid * L_) * 64 + lane;   // +64 per t

    float* ebase  = out + (size_t)(m * B_ + b0) * L_ * Q_;   // [row][t][col]
    float* ll_out = out + (size_t)M_ * B_ * L_ * Q_;

    float* rp[4];
#pragma unroll
    for (int r = 0; r < 4; ++r)
        rp[r] = ebase + (size_t)(krow * 4 + r) * (L_ * Q_) + wave * 64 + colq;

    // alpha write offsets: one u32 per row at psbase = wave*64 + colq*4
    int woff[4];
    {
        const int slot = wave * 4 + (colq >> 2);
        const int bis  = (colq & 3) << 2;
#pragma unroll
        for (int r = 0; r < 4; ++r) {
            int row = krow * 4 + r;
            woff[r] = row * 512 + ((slot ^ (row & 7)) << 4) + bis;
        }
    }
    // A-frag read offsets: 2 per kt
    int roff[4][2];
#pragma unroll
    for (int kt = 0; kt < 4; ++kt) {
        int s0 = kt * 8 + krow * 2;
        roff[kt][0] = colq * 512 + ((s0 ^ (colq & 7)) << 4);
        roff[kt][1] = colq * 512 + (((s0 + 1) ^ (colq & 7)) << 4);
    }

    const int wroff = ((colq & 7) * 4 + krow) * 16;
    const int wwoff = (wave * 4 + krow) * 16;

    float a[4][4];
    int   llE[4];
    int   Eprev[4];

    // ================= t = 0 =================
    uint4 ain = ab[0];
    {
        bfrag8 av = __builtin_bit_cast(bfrag8, ain);
        f32x4 ce[4];
#pragma unroll
        for (int nt = 0; nt < 4; ++nt) {
            ce[nt] = f32x4{0, 0, 0, 0};
            ce[nt] = __builtin_amdgcn_mfma_f32_16x16x32_bf16(av, ef[nt], ce[nt], 0, 0, 0);
        }
#pragma unroll
        for (int nt = 0; nt < 4; ++nt) {
            float iv = init_dist[m * Q_ + wave * 64 + nt * 16 + colq];
#pragma unroll
            for (int r = 0; r < 4; ++r)
                a[nt][r] = iv * ce[nt][r];
        }
        float p[4];
#pragma unroll
        for (int r = 0; r < 4; ++r)
            p[r] = red16(a[0][r] + a[1][r] + a[2][r] + a[3][r]);
        if (colq == 0) *(f32x4*)(wsB[0] + wwoff) = f32x4{p[0], p[1], p[2], p[3]};
        __syncthreads();
        f32x4 sv = *(const f32x4*)(wsB[0] + wroff);
#pragma unroll
        for (int r = 0; r < 4; ++r) {
            float shat = red16(sv[r]) * 0.5f;
            int D = (int)((__float_as_uint(shat) >> 23) & 0xffu) - 127;
            int E = D - 11;
            llE[r] = E; Eprev[r] = E;
            float kf = __uint_as_float((uint32_t)(127 - E) << 23);
            uint32_t pk = __builtin_amdgcn_cvt_pk_fp8_f32(
                fminf(a[0][r] * kf, 448.f), fminf(a[1][r] * kf, 448.f), 0, false);
            pk = __builtin_amdgcn_cvt_pk_fp8_f32(
                fminf(a[2][r] * kf, 448.f), fminf(a[3][r] * kf, 448.f), pk, true);
            *(uint32_t*)(&alpha8[0][woff[r]]) = pk;
        }
        __syncthreads();
    }
    uint4 ain_next = ab[64];   // t = 1

    // ================= t = 1 .. L-1 : ONE lgkm-only barrier per step ============
    for (int t = 1; t < L_; ++t) {
        const int pb = (t - 1) & 1, qb = t & 1;

        // (1) shadow read, then ALL 8 af b128 reads: LDS pipe streams from cycle 0.
        //     (sv first: LDS returns in order, so its consumer waits only 1 op.)
        f32x4 sv = *(const f32x4*)(wsB[pb] + wroff);
        u64x2 afq[8];
#pragma unroll
        for (int kt = 0; kt < 4; ++kt) {
            afq[2 * kt]     = *(const u64x2*)(&alpha8[pb][roff[kt][0]]);
            afq[2 * kt + 1] = *(const u64x2*)(&alpha8[pb][roff[kt][1]]);
        }

        // (2) global traffic under the LDS burst
        ain = ain_next;
        int tn = (t + 1 < L_) ? (t + 1) : t;
        ain_next = ab[(size_t)tn * 64];            // stays in flight across barrier

        // (3) shadow VALU: shat_{t-1} -> inv, E, kf
        float inv[4], kf[4];
        int Ecur[4];
#pragma unroll
        for (int r = 0; r < 4; ++r) {
            float shat = red16(sv[r]) * 0.5f;
            inv[r] = __builtin_amdgcn_rcpf(shat);
            int D = (int)((__float_as_uint(shat) >> 23) & 0xffu) - 127;
            Ecur[r] = D - Eprev[r] - 12;
            kf[r] = __uint_as_float((uint32_t)(127 - Ecur[r]) << 23);
        }

        // (4) deferred normalized store of forward_{t-1}
#pragma unroll
        for (int r = 0; r < 4; ++r) rp[r] += Q_;
#pragma unroll
        for (int nt = 0; nt < 4; ++nt)
#pragma unroll
            for (int r = 0; r < 4; ++r)
                rp[r][nt * 16 - Q_] = a[nt][r] * inv[r];

        // (5) MFMA block consuming afq regs (counted lgkm waits by compiler)
        bfrag8 av = __builtin_bit_cast(bfrag8, ain);
        f32x4 c[4], ce[4];
#pragma unroll
        for (int nt = 0; nt < 4; ++nt) { c[nt] = f32x4{0,0,0,0}; ce[nt] = f32x4{0,0,0,0}; }
        __builtin_amdgcn_s_setprio(1);
#pragma unroll
        for (int kt = 0; kt < 4; ++kt) {
            union Afrag { u64x2 h[2]; i32x8 v; } afr;
            afr.h[0] = afq[2 * kt];
            afr.h[1] = afq[2 * kt + 1];
            ce[kt] = __builtin_amdgcn_mfma_f32_16x16x32_bf16(av, ef[kt], ce[kt], 0, 0, 0);
#pragma unroll
            for (int nt = 0; nt < 4; ++nt)
                c[nt] = __builtin_amdgcn_mfma_scale_f32_16x16x128_f8f6f4(
                            afr.v, bf[nt][kt].v, c[nt],
                            0, 0,                    // cbsz=fp8, blgp=fp8
                            0, 0x7F7F7F7F,           // scale A = 1.0
                            0, 0x7F7F7F7F);          // scale B = 1.0
        }
        __builtin_amdgcn_s_setprio(0);

        // (6) â_t = ĉ · ê_t ; quantize+write alpha first, then row sums
#pragma unroll
        for (int nt = 0; nt < 4; ++nt)
#pragma unroll
            for (int r = 0; r < 4; ++r)
                a[nt][r] = c[nt][r] * ce[nt][r];

        if (t < L_ - 1) {
#pragma unroll
            for (int r = 0; r < 4; ++r) {
                llE[r] += Ecur[r]; Eprev[r] = Ecur[r];
                float k = kf[r];
                uint32_t pk = __builtin_amdgcn_cvt_pk_fp8_f32(
                    fminf(a[0][r] * k, 448.f), fminf(a[1][r] * k, 448.f), 0, false);
                pk = __builtin_amdgcn_cvt_pk_fp8_f32(
                    fminf(a[2][r] * k, 448.f), fminf(a[3][r] * k, 448.f), pk, true);
                *(uint32_t*)(&alpha8[qb][woff[r]]) = pk;
            }
        }

        float p[4];
#pragma unroll
        for (int r = 0; r < 4; ++r)
            p[r] = red16(a[0][r] + a[1][r] + a[2][r] + a[3][r]);
        if (colq == 0) *(f32x4*)(wsB[qb] + wwoff) = f32x4{p[0], p[1], p[2], p[3]};

        BARRIER();
    }

    // ================= final: normalize t = L-1, write ll =================
    {
        f32x4 sv = *(const f32x4*)(wsB[(L_ - 1) & 1] + wroff);
        float ll[4];
#pragma unroll
        for (int r = 0; r < 4; ++r) {
            float shat = red16(sv[r]) * 0.5f;
            float invr = __builtin_amdgcn_rcpf(shat);
#pragma unroll
            for (int nt = 0; nt < 4; ++nt)
                rp[r][nt * 16] = a[nt][r] * invr;
            ll[r] = LN2F * (8.0f + __log2f(shat) + (float)llE[r]);
        }
        if (wave == 0 && colq == 0) {
#pragma unroll
            for (int r = 0; r < 4; ++r)
                ll_out[m * B_ + b0 + krow * 4 + r] = ll[r];
        }
    }
}

// ---- fallback path (insufficient workspace): emission prekernel + fp32 recursion ----
__global__ __launch_bounds__(512) void emission_kernel(
    const float* __restrict__ inputs, const float* __restrict__ emit,
    float* __restrict__ out) {
    __shared__ float ein[LB * S_];
    const int tid = threadIdx.x;
    const int lt  = blockIdx.x % (L_ / LB);
    const int mb  = blockIdx.x / (L_ / LB);
    const int m   = mb / B_;
    const int b   = mb % B_;
    const int k   = tid;
    const float* inrow = inputs + ((size_t)(m * B_ + b) * L_ + (size_t)lt * LB) * S_;
    if (tid < LB * S_) ein[tid] = inrow[tid];
    float emv[S_];
    const float* em = emit + (size_t)m * S_ * Q_ + k;
#pragma unroll
    for (int s = 0; s < S_; ++s) emv[s] = em[(size_t)s * Q_];
    __syncthreads();
    float* orow = out + ((size_t)(m * B_ + b) * L_ + (size_t)lt * LB) * Q_ + k;
#pragma unroll
    for (int il = 0; il < LB; ++il) {
        float e = 0.f;
#pragma unroll
        for (int s = 0; s < S_; ++s) e = fmaf(ein[il * S_ + s], emv[s], e);
        orow[(size_t)il * Q_] = e;
    }
}

__global__ __launch_bounds__(512, 1) void hmm_fwd_f32(
    const float* __restrict__ init_dist,
    const float* __restrict__ trans,
    float* __restrict__ out)
{
    __shared__ float alphaF[Q_];
    __shared__ alignas(16) float apart[4][Q_];
    __shared__ float wred[8];
    const int tid  = threadIdx.x;
    const int m    = blockIdx.x / B_;
    const int b    = blockIdx.x % B_;
    const int k    = tid;
    const int k0   = (tid & 127) * 4;
    const int qh   = tid >> 7;
    const int lane = tid & 63;
    const int wav  = tid >> 6;
    float* erow   = out + (size_t)(m * B_ + b) * L_ * Q_;
    float* ll_out = out + (size_t)M_ * B_ * L_ * Q_;
    float ll = 0.f;
    {
        float e = erow[k];
        float a = init_dist[m * Q_ + k] * e;
        float r = a;
#pragma unroll
        for (int off = 32; off; off >>= 1) r += __shfl_xor(r, off, 64);
        if (lane == 0) wred[wav] = r;
        __syncthreads();
        float s = 0.f;
#pragma unroll
        for (int w = 0; w < 8; ++w) s += wred[w];
        ll = logf(s);
        float n = a * (1.0f / s);
        alphaF[k] = n;
        erow[k] = n;
        __syncthreads();
    }
    for (int t = 1; t < L_; ++t) {
        float e = erow[(size_t)t * Q_ + k];
        float4 acc = make_float4(0.f, 0.f, 0.f, 0.f);
        const float* tg = trans + (size_t)m * Q_ * Q_ + (size_t)(qh * 128) * Q_ + k0;
#pragma unroll 4
        for (int q = 0; q < 128; ++q) {
            float4 tv = *(const float4*)(tg + (size_t)q * Q_);
            float aq = alphaF[qh * 128 + q];
            acc.x = fmaf(aq, tv.x, acc.x);
            acc.y = fmaf(aq, tv.y, acc.y);
            acc.z = fmaf(aq, tv.z, acc.z);
            acc.w = fmaf(aq, tv.w, acc.w);
        }
        *(float4*)&apart[qh][k0] = acc;
        __syncthreads();
        float avs = apart[0][k] + apart[1][k] + apart[2][k] + apart[3][k];
        float a   = avs * e;
        float r = a;
#pragma unroll
        for (int off = 32; off; off >>= 1) r += __shfl_xor(r, off, 64);
        if (lane == 0) wred[wav] = r;
        __syncthreads();
        float s = 0.f;
#pragma unroll
        for (int w = 0; w < 8; ++w) s += wred[w];
        ll += logf(s);
        float n = a * (1.0f / s);
        alphaF[k] = n;
        erow[(size_t)t * Q_ + k] = n;
        __syncthreads();
    }
    if (tid == 0) ll_out[m * B_ + b] = ll;
}

extern "C" void kernel_launch(void* const* d_in, const int* in_sizes, int n_in,
                              void* d_out, int out_size, void* d_ws, size_t ws_size,
                              hipStream_t stream) {
    const float* inputs    = (const float*)d_in[0];
    const float* init_dist = (const float*)d_in[1];
    const float* trans     = (const float*)d_in[2];
    const float* emit      = (const float*)d_in[3];
    float* out             = (float*)d_out;

    const size_t bf_bytes = (size_t)M_ * 8 * 4 * 4 * 64 * 32;      // 512 KB
    const size_t ef_bytes = (size_t)M_ * 8 * 4 * 64 * 16;          // 64 KB
    const size_t af_bytes = (size_t)M_ * 4 * L_ * 64 * 16;         // 4 MB
    const bool mfma_path = (ws_size >= bf_bytes + ef_bytes + af_bytes);

    if (mfma_path) {
        uint32_t* Bf = (uint32_t*)d_ws;
        uint4* Ef = (uint4*)((char*)d_ws + bf_bytes);
        uint4* Af = (uint4*)((char*)d_ws + bf_bytes + ef_bytes);
        hipLaunchKernelGGL(pack_trans_frag, dim3((M_ * 8 * 4 * 4 * 64) / 256), dim3(256),
                           0, stream, trans, Bf);
        hipLaunchKernelGGL(pack_emit_frag, dim3((M_ * 8 * 4 * 64) / 256), dim3(256),
                           0, stream, emit, Ef);
        hipLaunchKernelGGL(pack_inputs_frag, dim3((M_ * 4 * L_ * 64) / 256), dim3(256),
                           0, stream, inputs, Af);
        hipLaunchKernelGGL(hmm_fwd_mfma, dim3(M_ * B_ / 16), dim3(NT), 0, stream,
                           init_dist, Bf, Ef, Af, out);
    } else {
        hipLaunchKernelGGL(emission_kernel, dim3(M_ * B_ * (L_ / LB)), dim3(512), 0, stream,
                           inputs, emit, out);
        hipLaunchKernelGGL(hmm_fwd_f32, dim3(M_ * B_), dim3(512), 0, stream,
                           init_dist, trans, out);
    }
}

// Round 21
// 748.012 us; speedup vs baseline: 11.3472x; 1.0007x over previous
//
#include <hip/hip_runtime.h>
#include <cstddef>
#include <cstdint>

// Problem constants: M,B,L,S,Q = 2,64,512,26,512
#define M_ 2
#define B_ 64
#define L_ 512
#define S_ 26
#define Q_ 512
#define NT 512
#define LB 16
#define TSCALE 256.0f           // trans fp8 scale
#define ETS (1.0f / 256.0f)     // folded into packed emit: cancels TSCALE each step
#define LN2F 0.6931471805599453f

typedef float f32x4 __attribute__((ext_vector_type(4)));
typedef short bfrag8 __attribute__((ext_vector_type(8)));               // 8 bf16
typedef int   i32x8  __attribute__((ext_vector_type(8)));               // 32B MFMA operand
typedef unsigned long long u64x2 __attribute__((ext_vector_type(2)));   // 16B LDS read

// workgroup barrier WITHOUT the vmcnt(0) drain __syncthreads carries.
#define BARRIER() asm volatile("s_waitcnt lgkmcnt(0)\n\ts_barrier" ::: "memory")

// ---- DPP helpers ----
template <int CTRL>
__device__ __forceinline__ float dpp_add(float v) {
    int x = __builtin_amdgcn_update_dpp(0, __builtin_bit_cast(int, v), CTRL, 0xF, 0xF, true);
    return v + __builtin_bit_cast(float, x);
}
__device__ __forceinline__ float red16(float v) {
    v = dpp_add<0xB1>(v);   // lane^1
    v = dpp_add<0x4E>(v);   // lane^2
    v = dpp_add<0x141>(v);  // row_half_mirror (quad^1)
    v = dpp_add<0x140>(v);  // row_mirror      (quad^3)
    return v;
}

// ---- encoders ----
__device__ __forceinline__ uint32_t enc_e4m3(float f) {
    if (!(f > 0.f)) return 0u;
    float v = fminf(f, 448.f);
    if (v < 0.015625f) return (uint32_t)rintf(v * 512.f);
    uint32_t u = __float_as_uint(v);
    u += 0x7FFFFu + ((u >> 20) & 1u);
    uint32_t e2  = ((u >> 23) & 0xffu) - 120u;
    uint32_t man = (u >> 20) & 7u;
    if (e2 > 15u || (e2 == 15u && man > 6u)) return 0x7Eu;
    return (e2 << 3) | man;
}
__device__ __forceinline__ uint32_t enc_bf16(float f) {
    uint32_t u = __float_as_uint(f);
    u += 0x7fffu + ((u >> 16) & 1u);      // RNE
    return u >> 16;
}

// ---- prep 1: trans*256 -> fp8 B-fragments for 16x16x128 MX MFMA ----
// PERMUTED k-axis: ps = wp*64 + cq*4 + ntq <-> s = wp*64 + ntq*16 + cq.
__global__ void pack_trans_frag(const float* __restrict__ trans,
                                uint32_t* __restrict__ Bf) {
    int idx  = blockIdx.x * blockDim.x + threadIdx.x;  // M*8*4*4*64 = 16384
    int lane = idx & 63;
    int kt   = (idx >> 6) & 3;
    int nt   = (idx >> 8) & 3;
    int wave = (idx >> 10) & 7;
    int m    = idx >> 13;
    int col  = wave * 64 + nt * 16 + (lane & 15);
    const float* tm = trans + (size_t)m * Q_ * Q_;
    uint32_t w[8];
#pragma unroll
    for (int d = 0; d < 8; ++d) {
        uint32_t v = 0;
#pragma unroll
        for (int b = 0; b < 4; ++b) {
            int j  = d * 4 + b;
            int ps = kt * 128 + (lane >> 4) * 32 + j;
            int s  = (ps & ~63) + (ps & 3) * 16 + ((ps >> 2) & 15);  // un-permute
            v |= enc_e4m3(tm[(size_t)s * Q_ + col] * TSCALE) << (8 * b);
        }
        w[d] = v;
    }
    uint32_t* dst = Bf + (size_t)idx * 8;
    *(uint4*)dst       = make_uint4(w[0], w[1], w[2], w[3]);
    *(uint4*)(dst + 4) = make_uint4(w[4], w[5], w[6], w[7]);
}

// ---- prep 2: emit*ETS -> bf16 B-fragments (K=32, s>=26 zero) ----
__global__ void pack_emit_frag(const float* __restrict__ emit, uint4* __restrict__ Ef) {
    int idx  = blockIdx.x * blockDim.x + threadIdx.x;  // M*8*4*64 = 4096
    int lane = idx & 63;
    int nt   = (idx >> 6) & 3;
    int wave = (idx >> 8) & 7;
    int m    = idx >> 11;
    int col  = wave * 64 + nt * 16 + (lane & 15);
    int s0   = (lane >> 4) * 8;
    uint32_t h[8];
#pragma unroll
    for (int i = 0; i < 8; ++i) {
        int s = s0 + i;
        h[i] = (s < S_) ? enc_bf16(emit[((size_t)m * S_ + s) * Q_ + col] * ETS) : 0u;
    }
    Ef[idx] = make_uint4(h[0] | (h[1] << 16), h[2] | (h[3] << 16),
                         h[4] | (h[5] << 16), h[6] | (h[7] << 16));
}

// ---- prep 3: inputs -> bf16 A-fragments per (block,t) ----
__global__ void pack_inputs_frag(const float* __restrict__ inputs, uint4* __restrict__ Af) {
    int idx  = blockIdx.x * blockDim.x + threadIdx.x;  // M*4*512*64 = 262144
    int lane = idx & 63;
    int t    = (idx >> 6) & 511;
    int bg   = (idx >> 15) & 3;
    int m    = idx >> 17;
    int colq = lane & 15, krow = lane >> 4;
    int b    = bg * 16 + colq;
    int k0   = krow * 8;
    const float* ip = inputs + ((size_t)(m * B_ + b) * L_ + t) * S_ + k0;
    uint32_t h[8];
#pragma unroll
    for (int i = 0; i < 8; ++i)
        h[i] = (k0 + i < S_) ? enc_bf16(ip[i]) : 0u;
    Af[((size_t)(m * 4 + bg) * L_ + t) * 64 + lane] =
        make_uint4(h[0] | (h[1] << 16), h[2] | (h[3] << 16),
                   h[4] | (h[5] << 16), h[6] | (h[7] << 16));
}

// ---- main: MX-scaled fp8 K=128 MFMA recursion + fused bf16 emission MFMA ----
// alpha LDS (16 rows x 512B): byte(row,ps) = row*512 + ((ps>>4)^(row&7))*16 + (ps&15).
// Step schedule: [barrier] -> sv read + ALL 8 af b128 reads (LDS pipe streams
// immediately) -> shadow VALU + deferred stores under the LDS burst -> MFMA
// block consuming afq regs (compiler-counted lgkmcnt) -> tail -> [barrier].
__global__ __launch_bounds__(NT, 2) void hmm_fwd_mfma(
    const float* __restrict__ init_dist,
    const uint32_t* __restrict__ Bf,
    const uint4* __restrict__ Ef,
    const uint4* __restrict__ Af,
    float* __restrict__ out)
{
    __shared__ char alpha8[2][16 * Q_];
    __shared__ char wsB[2][8 * 4 * 16];    // [buf][wave][krow] : f32x4

    const int tid  = threadIdx.x;
    const int wave = tid >> 6;
    const int lane = tid & 63;
    const int colq = lane & 15;            // = arow for the A-read
    const int krow = lane >> 4;
    const int bid  = blockIdx.x;           // 0..7
    const int m    = bid >> 2;
    const int b0   = (bid & 3) * 16;

    // B fragments (trans, fp8): 4nt x 4kt x 8 VGPR = 128 regs
    union Bfrag { unsigned long long q[4]; i32x8 v; };
    Bfrag bf[4][4];
    {
        const unsigned long long* bp =
            (const unsigned long long*)Bf + ((size_t)(m * 8 + wave) * 16) * 256 + lane * 4;
#pragma unroll
        for (int nt = 0; nt < 4; ++nt)
#pragma unroll
            for (int kt = 0; kt < 4; ++kt) {
                const unsigned long long* f = bp + (size_t)(nt * 4 + kt) * 256;
#pragma unroll
                for (int h = 0; h < 4; ++h) bf[nt][kt].q[h] = f[h];
            }
#pragma unroll
        for (int nt = 0; nt < 4; ++nt)
#pragma unroll
            for (int kt = 0; kt < 4; ++kt)
#pragma unroll
                for (int h = 0; h < 4; ++h)
                    asm volatile("" : "+v"(bf[nt][kt].q[h]));
    }
    // emit B fragments (bf16)
    bfrag8 ef[4];
#pragma unroll
    for (int nt = 0; nt < 4; ++nt)
        ef[nt] = __builtin_bit_cast(bfrag8,
            Ef[(((size_t)m * 8 + wave) * 4 + nt) * 64 + lane]);

    const uint4* ab = Af + ((size_t)bid * L_) * 64 + lane;   // +64 per t

    float* ebase  = out + (size_t)(m * B_ + b0) * L_ * Q_;   // [row][t][col]
    float* ll_out = out + (size_t)M_ * B_ * L_ * Q_;

    float* rp[4];
#pragma unroll
    for (int r = 0; r < 4; ++r)
        rp[r] = ebase + (size_t)(krow * 4 + r) * (L_ * Q_) + wave * 64 + colq;

    // alpha write offsets: one u32 per row at psbase = wave*64 + colq*4
    int woff[4];
    {
        const int slot = wave * 4 + (colq >> 2);
        const int bis  = (colq & 3) << 2;
#pragma unroll
        for (int r = 0; r < 4; ++r) {
            int row = krow * 4 + r;
            woff[r] = row * 512 + ((slot ^ (row & 7)) << 4) + bis;
        }
    }
    // A-frag read offsets: 2 per kt
    int roff[4][2];
#pragma unroll
    for (int kt = 0; kt < 4; ++kt) {
        int s0 = kt * 8 + krow * 2;
        roff[kt][0] = colq * 512 + ((s0 ^ (colq & 7)) << 4);
        roff[kt][1] = colq * 512 + (((s0 + 1) ^ (colq & 7)) << 4);
    }

    const int wroff = ((colq & 7) * 4 + krow) * 16;
    const int wwoff = (wave * 4 + krow) * 16;

    float a[4][4];
    int   llE[4];
    int   Eprev[4];

    // ================= t = 0 =================
    uint4 ain = ab[0];
    {
        bfrag8 av = __builtin_bit_cast(bfrag8, ain);
        f32x4 ce[4];
#pragma unroll
        for (int nt = 0; nt < 4; ++nt) {
            ce[nt] = f32x4{0, 0, 0, 0};
            ce[nt] = __builtin_amdgcn_mfma_f32_16x16x32_bf16(av, ef[nt], ce[nt], 0, 0, 0);
        }
#pragma unroll
        for (int nt = 0; nt < 4; ++nt) {
            float iv = init_dist[m * Q_ + wave * 64 + nt * 16 + colq];
#pragma unroll
            for (int r = 0; r < 4; ++r)
                a[nt][r] = iv * ce[nt][r];
        }
        float p[4];
#pragma unroll
        for (int r = 0; r < 4; ++r)
            p[r] = red16(a[0][r] + a[1][r] + a[2][r] + a[3][r]);
        if (colq == 0) *(f32x4*)(wsB[0] + wwoff) = f32x4{p[0], p[1], p[2], p[3]};
        __syncthreads();
        f32x4 sv = *(const f32x4*)(wsB[0] + wroff);
#pragma unroll
        for (int r = 0; r < 4; ++r) {
            float shat = red16(sv[r]) * 0.5f;
            int D = (int)((__float_as_uint(shat) >> 23) & 0xffu) - 127;
            int E = D - 11;
            llE[r] = E; Eprev[r] = E;
            float kf = __uint_as_float((uint32_t)(127 - E) << 23);
            uint32_t pk = __builtin_amdgcn_cvt_pk_fp8_f32(
                fminf(a[0][r] * kf, 448.f), fminf(a[1][r] * kf, 448.f), 0, false);
            pk = __builtin_amdgcn_cvt_pk_fp8_f32(
                fminf(a[2][r] * kf, 448.f), fminf(a[3][r] * kf, 448.f), pk, true);
            *(uint32_t*)(&alpha8[0][woff[r]]) = pk;
        }
        __syncthreads();
    }
    uint4 ain_next = ab[64];   // t = 1

    // ================= t = 1 .. L-1 : ONE lgkm-only barrier per step ============
    for (int t = 1; t < L_; ++t) {
        const int pb = (t - 1) & 1, qb = t & 1;

        // (1) shadow read, then ALL 8 af b128 reads: LDS pipe streams from cycle 0.
        f32x4 sv = *(const f32x4*)(wsB[pb] + wroff);
        u64x2 afq[8];
#pragma unroll
        for (int kt = 0; kt < 4; ++kt) {
            afq[2 * kt]     = *(const u64x2*)(&alpha8[pb][roff[kt][0]]);
            afq[2 * kt + 1] = *(const u64x2*)(&alpha8[pb][roff[kt][1]]);
        }

        // (2) global traffic under the LDS burst
        ain = ain_next;
        int tn = (t + 1 < L_) ? (t + 1) : t;
        ain_next = ab[(size_t)tn * 64];            // stays in flight across barrier

        // (3) shadow VALU: shat_{t-1} -> inv, E, kf
        float inv[4], kf[4];
        int Ecur[4];
#pragma unroll
        for (int r = 0; r < 4; ++r) {
            float shat = red16(sv[r]) * 0.5f;
            inv[r] = __builtin_amdgcn_rcpf(shat);
            int D = (int)((__float_as_uint(shat) >> 23) & 0xffu) - 127;
            Ecur[r] = D - Eprev[r] - 12;
            kf[r] = __uint_as_float((uint32_t)(127 - Ecur[r]) << 23);
        }

        // (4) deferred normalized store of forward_{t-1}
#pragma unroll
        for (int r = 0; r < 4; ++r) rp[r] += Q_;
#pragma unroll
        for (int nt = 0; nt < 4; ++nt)
#pragma unroll
            for (int r = 0; r < 4; ++r)
                rp[r][nt * 16 - Q_] = a[nt][r] * inv[r];

        // (5) MFMA block consuming afq regs (counted lgkm waits by compiler)
        bfrag8 av = __builtin_bit_cast(bfrag8, ain);
        f32x4 c[4], ce[4];
#pragma unroll
        for (int nt = 0; nt < 4; ++nt) { c[nt] = f32x4{0,0,0,0}; ce[nt] = f32x4{0,0,0,0}; }
        __builtin_amdgcn_s_setprio(1);
#pragma unroll
        for (int kt = 0; kt < 4; ++kt) {
            union Afrag { u64x2 h[2]; i32x8 v; } afr;
            afr.h[0] = afq[2 * kt];
            afr.h[1] = afq[2 * kt + 1];
            ce[kt] = __builtin_amdgcn_mfma_f32_16x16x32_bf16(av, ef[kt], ce[kt], 0, 0, 0);
#pragma unroll
            for (int nt = 0; nt < 4; ++nt)
                c[nt] = __builtin_amdgcn_mfma_scale_f32_16x16x128_f8f6f4(
                            afr.v, bf[nt][kt].v, c[nt],
                            0, 0,                    // cbsz=fp8, blgp=fp8
                            0, 0x7F7F7F7F,           // scale A = 1.0
                            0, 0x7F7F7F7F);          // scale B = 1.0
        }
        __builtin_amdgcn_s_setprio(0);

        // (6) â_t = ĉ · ê_t ; quantize+write alpha first, then row sums
#pragma unroll
        for (int nt = 0; nt < 4; ++nt)
#pragma unroll
            for (int r = 0; r < 4; ++r)
                a[nt][r] = c[nt][r] * ce[nt][r];

        if (t < L_ - 1) {
#pragma unroll
            for (int r = 0; r < 4; ++r) {
                llE[r] += Ecur[r]; Eprev[r] = Ecur[r];
                float k = kf[r];
                uint32_t pk = __builtin_amdgcn_cvt_pk_fp8_f32(
                    fminf(a[0][r] * k, 448.f), fminf(a[1][r] * k, 448.f), 0, false);
                pk = __builtin_amdgcn_cvt_pk_fp8_f32(
                    fminf(a[2][r] * k, 448.f), fminf(a[3][r] * k, 448.f), pk, true);
                *(uint32_t*)(&alpha8[qb][woff[r]]) = pk;
            }
        }

        float p[4];
#pragma unroll
        for (int r = 0; r < 4; ++r)
            p[r] = red16(a[0][r] + a[1][r] + a[2][r] + a[3][r]);
        if (colq == 0) *(f32x4*)(wsB[qb] + wwoff) = f32x4{p[0], p[1], p[2], p[3]};

        BARRIER();
    }

    // ================= final: normalize t = L-1, write ll =================
    {
        f32x4 sv = *(const f32x4*)(wsB[(L_ - 1) & 1] + wroff);
        float ll[4];
#pragma unroll
        for (int r = 0; r < 4; ++r) {
            float shat = red16(sv[r]) * 0.5f;
            float invr = __builtin_amdgcn_rcpf(shat);
#pragma unroll
            for (int nt = 0; nt < 4; ++nt)
                rp[r][nt * 16] = a[nt][r] * invr;
            ll[r] = LN2F * (8.0f + __log2f(shat) + (float)llE[r]);
        }
        if (wave == 0 && colq == 0) {
#pragma unroll
            for (int r = 0; r < 4; ++r)
                ll_out[m * B_ + b0 + krow * 4 + r] = ll[r];
        }
    }
}

// ---- fallback path (insufficient workspace): emission prekernel + fp32 recursion ----
__global__ __launch_bounds__(512) void emission_kernel(
    const float* __restrict__ inputs, const float* __restrict__ emit,
    float* __restrict__ out) {
    __shared__ float ein[LB * S_];
    const int tid = threadIdx.x;
    const int lt  = blockIdx.x % (L_ / LB);
    const int mb  = blockIdx.x / (L_ / LB);
    const int m   = mb / B_;
    const int b   = mb % B_;
    const int k   = tid;
    const float* inrow = inputs + ((size_t)(m * B_ + b) * L_ + (size_t)lt * LB) * S_;
    if (tid < LB * S_) ein[tid] = inrow[tid];
    float emv[S_];
    const float* em = emit + (size_t)m * S_ * Q_ + k;
#pragma unroll
    for (int s = 0; s < S_; ++s) emv[s] = em[(size_t)s * Q_];
    __syncthreads();
    float* orow = out + ((size_t)(m * B_ + b) * L_ + (size_t)lt * LB) * Q_ + k;
#pragma unroll
    for (int il = 0; il < LB; ++il) {
        float e = 0.f;
#pragma unroll
        for (int s = 0; s < S_; ++s) e = fmaf(ein[il * S_ + s], emv[s], e);
        orow[(size_t)il * Q_] = e;
    }
}

__global__ __launch_bounds__(512, 1) void hmm_fwd_f32(
    const float* __restrict__ init_dist,
    const float* __restrict__ trans,
    float* __restrict__ out)
{
    __shared__ float alphaF[Q_];
    __shared__ alignas(16) float apart[4][Q_];
    __shared__ float wred[8];
    const int tid  = threadIdx.x;
    const int m    = blockIdx.x / B_;
    const int b    = blockIdx.x % B_;
    const int k    = tid;
    const int k0   = (tid & 127) * 4;
    const int qh   = tid >> 7;
    const int lane = tid & 63;
    const int wav  = tid >> 6;
    float* erow   = out + (size_t)(m * B_ + b) * L_ * Q_;
    float* ll_out = out + (size_t)M_ * B_ * L_ * Q_;
    float ll = 0.f;
    {
        float e = erow[k];
        float a = init_dist[m * Q_ + k] * e;
        float r = a;
#pragma unroll
        for (int off = 32; off; off >>= 1) r += __shfl_xor(r, off, 64);
        if (lane == 0) wred[wav] = r;
        __syncthreads();
        float s = 0.f;
#pragma unroll
        for (int w = 0; w < 8; ++w) s += wred[w];
        ll = logf(s);
        float n = a * (1.0f / s);
        alphaF[k] = n;
        erow[k] = n;
        __syncthreads();
    }
    for (int t = 1; t < L_; ++t) {
        float e = erow[(size_t)t * Q_ + k];
        float4 acc = make_float4(0.f, 0.f, 0.f, 0.f);
        const float* tg = trans + (size_t)m * Q_ * Q_ + (size_t)(qh * 128) * Q_ + k0;
#pragma unroll 4
        for (int q = 0; q < 128; ++q) {
            float4 tv = *(const float4*)(tg + (size_t)q * Q_);
            float aq = alphaF[qh * 128 + q];
            acc.x = fmaf(aq, tv.x, acc.x);
            acc.y = fmaf(aq, tv.y, acc.y);
            acc.z = fmaf(aq, tv.z, acc.z);
            acc.w = fmaf(aq, tv.w, acc.w);
        }
        *(float4*)&apart[qh][k0] = acc;
        __syncthreads();
        float avs = apart[0][k] + apart[1][k] + apart[2][k] + apart[3][k];
        float a   = avs * e;
        float r = a;
#pragma unroll
        for (int off = 32; off; off >>= 1) r += __shfl_xor(r, off, 64);
        if (lane == 0) wred[wav] = r;
        __syncthreads();
        float s = 0.f;
#pragma unroll
        for (int w = 0; w < 8; ++w) s += wred[w];
        ll += logf(s);
        float n = a * (1.0f / s);
        alphaF[k] = n;
        erow[(size_t)t * Q_ + k] = n;
        __syncthreads();
    }
    if (tid == 0) ll_out[m * B_ + b] = ll;
}

extern "C" void kernel_launch(void* const* d_in, const int* in_sizes, int n_in,
                              void* d_out, int out_size, void* d_ws, size_t ws_size,
                              hipStream_t stream) {
    const float* inputs    = (const float*)d_in[0];
    const float* init_dist = (const float*)d_in[1];
    const float* trans     = (const float*)d_in[2];
    const float* emit      = (const float*)d_in[3];
    float* out             = (float*)d_out;

    const size_t bf_bytes = (size_t)M_ * 8 * 4 * 4 * 64 * 32;      // 512 KB
    const size_t ef_bytes = (size_t)M_ * 8 * 4 * 64 * 16;          // 64 KB
    const size_t af_bytes = (size_t)M_ * 4 * L_ * 64 * 16;         // 4 MB
    const bool mfma_path = (ws_size >= bf_bytes + ef_bytes + af_bytes);

    if (mfma_path) {
        uint32_t* Bf = (uint32_t*)d_ws;
        uint4* Ef = (uint4*)((char*)d_ws + bf_bytes);
        uint4* Af = (uint4*)((char*)d_ws + bf_bytes + ef_bytes);
        hipLaunchKernelGGL(pack_trans_frag, dim3((M_ * 8 * 4 * 4 * 64) / 256), dim3(256),
                           0, stream, trans, Bf);
        hipLaunchKernelGGL(pack_emit_frag, dim3((M_ * 8 * 4 * 64) / 256), dim3(256),
                           0, stream, emit, Ef);
        hipLaunchKernelGGL(pack_inputs_frag, dim3((M_ * 4 * L_ * 64) / 256), dim3(256),
                           0, stream, inputs, Af);
        hipLaunchKernelGGL(hmm_fwd_mfma, dim3(M_ * B_ / 16), dim3(NT), 0, stream,
                           init_dist, Bf, Ef, Af, out);
    } else {
        hipLaunchKernelGGL(emission_kernel, dim3(M_ * B_ * (L_ / LB)), dim3(512), 0, stream,
                           inputs, emit, out);
        hipLaunchKernelGGL(hmm_fwd_f32, dim3(M_ * B_), dim3(512), 0, stream,
                           init_dist, trans, out);
    }
}